// Round 9
// baseline (262.566 us; speedup 1.0000x reference)
//
#include <hip/hip_runtime.h>
#include <hip/hip_bf16.h>
#include <math.h>

#define B 4
#define A 256
#define NN 64
#define NCB 128
#define NF 128
#define NSB 50
#define BA (B*A)
#define PAIRS (BA*NN)

typedef __bf16 bf;
typedef __attribute__((ext_vector_type(8))) __bf16 bfrag8;
typedef __attribute__((ext_vector_type(4))) float ffrag4;

// ---- module-scope scratch (never touches inputs / d_ws) ----
__device__ __attribute__((aligned(16))) bf    g_yib[BA*NF];             // bf16(xi @ in2f_W)
__device__ __attribute__((aligned(16))) bf    g_vij[(size_t)PAIRS*NCB]; // bf16 vij stash (16 MB)
__device__ __attribute__((aligned(16))) float g_vik[BA*NCB*3];          // fp32 Vik rows [ba][c*3+d]
// transposed bf16 weights, layout [n][k] (k contiguous). tf1 padded to K=64.
__device__ __attribute__((aligned(16))) bf g_tf1[NF*64];
__device__ __attribute__((aligned(16))) bf g_tf2[NF*NF];
__device__ __attribute__((aligned(16))) bf g_tfo[NF*NF];
__device__ __attribute__((aligned(16))) bf g_tp1[NF*NF];
__device__ __attribute__((aligned(16))) bf g_tp2[NF*NF];
__device__ __attribute__((aligned(16))) bf g_te1[NF*NF];
__device__ __attribute__((aligned(16))) bf g_te2[NF*NF];

// fast ssp: softplus(x)-ln2 via hw v_exp_f32/v_log_f32
__device__ __forceinline__ float ssp(float x){
    float e = __expf(-fabsf(x));
    return fmaxf(x, 0.f) + __logf(1.f + e) - 0.6931471805599453f;
}

// XOR bank swizzle: rows are 256 B (mod 128 == 0), so spreading the 16-B slot
// by row&7 makes frag reads (16 lanes stride-256B at same in-row offset)
// conflict-free. Writer and reader MUST both apply it (involution).
__device__ __forceinline__ int swz(int row, int off){ return off ^ ((row & 7) << 4); }

// ---- weight pre-transpose: W[k][n] fp32 -> Wt[n][k] bf16 (tf1 K-pad to 64) ----
__global__ __launch_bounds__(256)
void k_wt(const float* __restrict__ f1, const float* __restrict__ f2,
          const float* __restrict__ fo, const float* __restrict__ p1,
          const float* __restrict__ p2, const float* __restrict__ e1,
          const float* __restrict__ e2){
    int s = blockIdx.x >> 3, part = blockIdx.x & 7;
    const float* src; bf* dst; int kb, realK;
    if (s == 0){ src = f1; dst = g_tf1; kb = 6; realK = NSB; }
    else {
        kb = 7; realK = 128;
        src = (s==1)?f2:(s==2)?fo:(s==3)?p1:(s==4)?p2:(s==5)?e1:e2;
        dst = (s==1)?g_tf2:(s==2)?g_tfo:(s==3)?g_tp1:(s==4)?g_tp2:(s==5)?g_te1:g_te2;
    }
    int total = NF << kb;
    int chunk = total >> 3;
    int end = (part + 1) * chunk;
    for (int e = part*chunk + threadIdx.x; e < end; e += 256){
        int n = e >> kb, k = e & ((1<<kb)-1);
        dst[e] = (k < realK) ? (bf)src[k*NF + n] : (bf)0.f;
    }
}

// ---- g_yib[row][f] = bf16( xi[row,:] @ in2f_W[:,f] ) ----
__global__ __launch_bounds__(NF)
void k_yi(const float* __restrict__ xi, const float* __restrict__ W){
    int row = blockIdx.x, f = threadIdx.x;
    __shared__ float x[NCB];
    x[f] = xi[row*NCB + f];
    __syncthreads();
    float s = 0.f;
    #pragma unroll 16
    for (int c = 0; c < NCB; c++) s += x[c]*W[c*NF + f];
    g_yib[row*NF + f] = (bf)s;
}

// ---- swizzled staging: global [n][k] rows -> sW rows of 256 B (128) / 128 B (64) ----
__device__ __forceinline__ void stage_w128s(char* __restrict__ sWb, const bf* __restrict__ g,
                                            int half, int tid){
    #pragma unroll
    for (int i = 0; i < 4; i++){
        int cid = i*256 + tid;                 // 1024 x 16B chunks
        int r = cid >> 4, ch = cid & 15;
        *(bfrag8*)(sWb + r*256 + swz(r, ch*16)) =
            *(const bfrag8*)((const char*)g + (size_t)(half*64 + r)*256 + ch*16);
    }
}
__device__ __forceinline__ void stage_w64s(char* __restrict__ sWb, const bf* __restrict__ g,
                                           int half, int tid){
    #pragma unroll
    for (int i = 0; i < 2; i++){
        int cid = i*256 + tid;                 // 512 x 16B chunks
        int r = cid >> 3, ch = cid & 7;
        *(bfrag8*)(sWb + r*128 + swz(r, ch*16)) =
            *(const bfrag8*)((const char*)g + (size_t)(half*64 + r)*128 + ch*16);
    }
}

// ---- one K=128 stage: wave tile 32 rows x 32 cols, B-frags reused over 2 row-tiles ----
template<class EPI>
__device__ __forceinline__ void stageX(const bf* __restrict__ gW, const bfrag8* afr,
                                       char* __restrict__ sWb, int tid,
                                       int cg, int q, int c16, EPI epi){
    #pragma unroll
    for (int half = 0; half < 2; half++){
        stage_w128s(sWb, gW, half, tid);
        __syncthreads();
        #pragma unroll
        for (int ntl = 0; ntl < 2; ntl++){
            int n = cg*32 + ntl*16 + c16;
            bfrag8 bfr[4];
            #pragma unroll
            for (int kt = 0; kt < 4; kt++)
                bfr[kt] = *(const bfrag8*)(sWb + n*256 + swz(n, kt*64 + q*16));
            #pragma unroll
            for (int mt = 0; mt < 2; mt++){
                ffrag4 a = {0.f,0.f,0.f,0.f};
                #pragma unroll
                for (int kt = 0; kt < 4; kt++)
                    a = __builtin_amdgcn_mfma_f32_16x16x32_bf16(afr[mt*4+kt], bfr[kt], a, 0, 0, 0);
                epi(half, ntl, mt, a);
            }
        }
        __syncthreads();
    }
}

// A-frags: 8 frags (2 row-tiles x 4 k-tiles) from swizzled sX.
// MUST be called between the post-epi barrier and the next stage-sync
// (rows are written by two waves -> not wave-private).
#define RDA8(DST) { _Pragma("unroll") for (int mt = 0; mt < 2; mt++) \
    { _Pragma("unroll") for (int kt = 0; kt < 4; kt++){ \
        int r = rg2*32 + mt*16 + c16; \
        DST[mt*4+kt] = *(const bfrag8*)(sXb + r*256 + swz(r, kt*64 + q*16)); } } }

__global__ __launch_bounds__(256, 4)
void k_main(const float* __restrict__ r_ij, const float* __restrict__ cos_ij,
            const float* __restrict__ f_ij, const float* __restrict__ mask,
            const int* __restrict__ neighbors,
            const float* __restrict__ fb1, const float* __restrict__ fb2,
            const float* __restrict__ f2b,
            const float* __restrict__ aW1, const float* __restrict__ ab1,
            const float* __restrict__ aW2, const float* __restrict__ ab2,
            const float* __restrict__ pb1, const float* __restrict__ pb2,
            const float* __restrict__ eb1, const float* __restrict__ eb2,
            float* __restrict__ out_vi){
    const int tid  = threadIdx.x;
    const int ba   = blockIdx.x;          // atom (b*A + a)
    const int b    = ba >> 8;
    const int w    = tid >> 6;            // wave 0..3
    const int lane = tid & 63;
    const int q    = lane >> 4;
    const int c16  = lane & 15;
    const int rg2  = w & 1;               // row group: rows rg2*32 .. +31
    const int cg   = w >> 1;              // col group (within 64-col half): cg*32 .. +31

    __shared__ __attribute__((aligned(16))) char sWb[64*256];   // 16 KB swizzled weights
    __shared__ __attribute__((aligned(16))) char sXb[64*256];   // 16 KB swizzled activations
    __shared__ float sCosM[64*4];
    __shared__ float sCr[64];
    __shared__ int   sJb[64];

    // ---- preload: f -> sX swizzled (K zero-padded to 64), block-wide ----
    #pragma unroll
    for (int i = 0; i < 16; i++){
        int e = tid + i*256;                   // 64 rows x 64 cols
        int row = e >> 6, colk = e & 63;
        float v = (colk < NSB) ? f_ij[((size_t)ba*64 + row)*NSB + colk] : 0.f;
        *(bf*)(sXb + row*256 + swz(row, colk*2)) = (bf)v;
    }
    if (tid < 64){
        int p = ba*64 + tid;
        sCosM[tid*4+0] = cos_ij[p*3+0];
        sCosM[tid*4+1] = cos_ij[p*3+1];
        sCosM[tid*4+2] = cos_ij[p*3+2];
        sCosM[tid*4+3] = mask[p];
        float r = r_ij[p];
        sCr[tid] = (r < 5.f) ? 0.5f*(__cosf(r*0.62831853071795864769f) + 1.f) : 0.f;
        int j = neighbors[p] & (A-1);
        sJb[tid] = (b*A + j)*NF;
    }
    __syncthreads();                           // rows now cross-wave: barrier needed

    bfrag8 afrA[8], afrV[8];
    float vsAll[4] = {0.f, 0.f, 0.f, 0.f};
    float vkAll[4][3];
    #pragma unroll
    for (int t = 0; t < 4; t++){ vkAll[t][0]=0.f; vkAll[t][1]=0.f; vkAll[t][2]=0.f; }

    // ===== S1: h1 = ssp(f @ fW1 + fb1) -> sX  (K=64, stride-128 sW) =====
    bfrag8 afr1[4];
    #pragma unroll
    for (int mt = 0; mt < 2; mt++)
        #pragma unroll
        for (int kt = 0; kt < 2; kt++){
            int r = rg2*32 + mt*16 + c16;
            afr1[mt*2+kt] = *(const bfrag8*)(sXb + r*256 + swz(r, kt*64 + q*16));
        }
    #pragma unroll
    for (int half = 0; half < 2; half++){
        stage_w64s(sWb, g_tf1, half, tid);
        __syncthreads();
        #pragma unroll
        for (int ntl = 0; ntl < 2; ntl++){
            int n = cg*32 + ntl*16 + c16;
            bfrag8 bfr[2];
            #pragma unroll
            for (int kt = 0; kt < 2; kt++)
                bfr[kt] = *(const bfrag8*)(sWb + n*128 + swz(n, kt*64 + q*16));
            #pragma unroll
            for (int mt = 0; mt < 2; mt++){
                ffrag4 a = {0.f,0.f,0.f,0.f};
                #pragma unroll
                for (int kt = 0; kt < 2; kt++)
                    a = __builtin_amdgcn_mfma_f32_16x16x32_bf16(afr1[mt*2+kt], bfr[kt], a, 0, 0, 0);
                int col = half*64 + cg*32 + ntl*16 + c16;
                float bias = fb1[col];
                #pragma unroll
                for (int rg = 0; rg < 4; rg++){
                    int row = rg2*32 + mt*16 + q*4 + rg;
                    *(bf*)(sXb + row*256 + swz(row, col*2)) = (bf)ssp(a[rg] + bias);
                }
            }
        }
        __syncthreads();
    }
    RDA8(afrA);                                // h1

    // ===== S2: Wf = (h1 @ fW2 + fb2)*C ; u = yj*Wf -> sX =====
    stageX(g_tf2, afrA, sWb, tid, cg, q, c16, [&](int h, int ntl, int mt, ffrag4 a){
        int col = h*64 + cg*32 + ntl*16 + c16;
        float bias = fb2[col];
        #pragma unroll
        for (int rg = 0; rg < 4; rg++){
            int row = rg2*32 + mt*16 + q*4 + rg;
            float wf = (a[rg] + bias) * sCr[row];
            *(bf*)(sXb + row*256 + swz(row, col*2)) = (bf)((float)g_yib[sJb[row] + col] * wf);
        }
    });
    RDA8(afrA);                                // u

    // ===== S3: v = ssp(u @ f2W + f2b) -> sX ; vsum partials =====
    stageX(g_tfo, afrA, sWb, tid, cg, q, c16, [&](int h, int ntl, int mt, ffrag4 a){
        int col = h*64 + cg*32 + ntl*16 + c16;
        float bias = f2b[col];
        #pragma unroll
        for (int rg = 0; rg < 4; rg++){
            int row = rg2*32 + mt*16 + q*4 + rg;
            float v = ssp(a[rg] + bias);
            *(bf*)(sXb + row*256 + swz(row, col*2)) = (bf)v;
            vsAll[h*2 + ntl] += v * sCosM[row*4+3];
        }
    });
    RDA8(afrV);                                // v — held in regs for S4 AND S6

    // ===== S4: hp = ssp(v @ pW1 + pb1) -> sX =====
    stageX(g_tp1, afrV, sWb, tid, cg, q, c16, [&](int h, int ntl, int mt, ffrag4 a){
        int col = h*64 + cg*32 + ntl*16 + c16;
        float bias = pb1[col];
        #pragma unroll
        for (int rg = 0; rg < 4; rg++){
            int row = rg2*32 + mt*16 + q*4 + rg;
            *(bf*)(sXb + row*256 + swz(row, col*2)) = (bf)ssp(a[rg] + bias);
        }
    });
    RDA8(afrA);                                // hp

    // ===== S5: vij = hp @ pW2 + pb2 -> sX (linear) =====
    stageX(g_tp2, afrA, sWb, tid, cg, q, c16, [&](int h, int ntl, int mt, ffrag4 a){
        int col = h*64 + cg*32 + ntl*16 + c16;
        float bias = pb2[col];
        #pragma unroll
        for (int rg = 0; rg < 4; rg++){
            int row = rg2*32 + mt*16 + q*4 + rg;
            *(bf*)(sXb + row*256 + swz(row, col*2)) = (bf)(a[rg] + bias);
        }
    });
    // stream vij -> g_vij (block-wide, de-swizzled read; before S6's stage-sync)
    #pragma unroll
    for (int i = 0; i < 4; i++){
        int cid = i*256 + tid;
        int r = cid >> 4, ch = cid & 15;
        *(bfrag8*)&g_vij[((size_t)ba*64 + r)*128 + ch*8] =
            *(const bfrag8*)(sXb + r*256 + swz(r, ch*16));
    }

    // ===== S6: he = ssp(v @ eW1 + eb1) -> sX  (input afrV, still live) =====
    stageX(g_te1, afrV, sWb, tid, cg, q, c16, [&](int h, int ntl, int mt, ffrag4 a){
        int col = h*64 + cg*32 + ntl*16 + c16;
        float bias = eb1[col];
        #pragma unroll
        for (int rg = 0; rg < 4; rg++){
            int row = rg2*32 + mt*16 + q*4 + rg;
            *(bf*)(sXb + row*256 + swz(row, col*2)) = (bf)ssp(a[rg] + bias);
        }
    });
    RDA8(afrA);                                // he

    // ===== S7: vik = he @ eW2 + eb2 ; Vik partials (registers only) =====
    stageX(g_te2, afrA, sWb, tid, cg, q, c16, [&](int h, int ntl, int mt, ffrag4 a){
        float bias = eb2[h*64 + cg*32 + ntl*16 + c16];
        #pragma unroll
        for (int rg = 0; rg < 4; rg++){
            int row = rg2*32 + mt*16 + q*4 + rg;
            float vik = (a[rg] + bias) * sCosM[row*4+3];
            vkAll[h*2 + ntl][0] += vik * sCosM[row*4+0];
            vkAll[h*2 + ntl][1] += vik * sCosM[row*4+1];
            vkAll[h*2 + ntl][2] += vik * sCosM[row*4+2];
        }
    });

    // ===== finale: cross-wave reduction; sXb reused as scratch =====
    __syncthreads();
    float* const sVs   = (float*)sXb;            // 4*64 floats  (1 KB)
    float* const sVk   = (float*)(sXb + 1024);   // 4*192 floats (3 KB)
    float* const sVsum = (float*)(sXb + 4096);   // 128 floats
    float* const sHa   = (float*)(sXb + 4608);   // 128 floats
    #pragma unroll
    for (int s = 0; s < 4; s++){
        float v = vsAll[s];
        v += __shfl_xor(v, 16);
        v += __shfl_xor(v, 32);
        if (q == 0) sVs[w*64 + s*16 + c16] = v;
    }
    #pragma unroll
    for (int s = 0; s < 4; s++){
        #pragma unroll
        for (int d = 0; d < 3; d++){
            float v = vkAll[s][d];
            v += __shfl_xor(v, 16);
            v += __shfl_xor(v, 32);
            if (q == 0) sVk[w*192 + (s*16 + c16)*3 + d] = v;
        }
    }
    __syncthreads();

    // combine: col c covered by waves {2*cgc, 2*cgc+1} at slot h*2+ntl
    if (tid < 128){
        int c = tid;
        int h = c >> 6, chi = c & 63, cgc = chi >> 5, ntl = (chi >> 4) & 1, cc = c & 15;
        int s = h*2 + ntl;
        sVsum[c] = sVs[(cgc*2)*64 + s*16 + cc] + sVs[(cgc*2+1)*64 + s*16 + cc];
    }
    for (int e = tid; e < 384; e += 256){
        int c = e/3, d = e - c*3;
        int h = c >> 6, chi = c & 63, cgc = chi >> 5, ntl = (chi >> 4) & 1, cc = c & 15;
        int s = h*2 + ntl;
        g_vik[ba*384 + e] = sVk[(cgc*2)*192 + (s*16 + cc)*3 + d]
                          + sVk[(cgc*2+1)*192 + (s*16 + cc)*3 + d];
    }
    __syncthreads();
    if (tid < 128){
        float acc2 = ab1[tid];
        #pragma unroll 16
        for (int k = 0; k < 128; k++) acc2 += sVsum[k]*aW1[k*128 + tid];
        sHa[tid] = ssp(acc2);
    }
    __syncthreads();
    if (tid < 128){
        float acc2 = ab2[tid];
        #pragma unroll 16
        for (int k = 0; k < 128; k++) acc2 += sHa[k]*aW2[k*128 + tid];
        out_vi[ba*128 + tid] = acc2;
    }
}

// ---- V[p,c,d] = vij[p,c]*cos[p,d] + Vik[ba] + Vik[j]  (r5 version, unchanged) ----
__global__ __launch_bounds__(256)
void k_V(const float* __restrict__ cos_ij, const int* __restrict__ nbrs,
         float* __restrict__ outV){
    const int ba  = blockIdx.x;
    const int b   = ba >> 8;
    const int tid = threadIdx.x;
    __shared__ __attribute__((aligned(16))) bf sVij[64*128];   // 16 KB
    __shared__ float sVa[384];
    __shared__ float sC[64*4];
    __shared__ int   sJ[64];
    #pragma unroll
    for (int i = 0; i < 4; i++){
        int e8 = tid + i*256;
        *(bfrag8*)&sVij[e8*8] = *(const bfrag8*)&g_vij[(size_t)ba*8192 + e8*8];
    }
    for (int e = tid; e < 384; e += 256) sVa[e] = g_vik[ba*384 + e];
    if (tid < 64){
        int p = ba*64 + tid;
        sJ[tid] = (b*A + (nbrs[p] & (A-1)))*384;
        sC[tid*4+0] = cos_ij[p*3+0];
        sC[tid*4+1] = cos_ij[p*3+1];
        sC[tid*4+2] = cos_ij[p*3+2];
    }
    __syncthreads();
    float* const oBase = outV + (size_t)ba*24576;
    #pragma unroll 4
    for (int it = 0; it < 24; it++){
        int idx = (it*256 + tid)*4;
        int pl  = idx / 384;
        int e0  = idx - pl*384;
        ffrag4 va = *(const ffrag4*)&sVa[e0];
        ffrag4 vj = *(const ffrag4*)(g_vik + sJ[pl] + e0);
        ffrag4 o;
        #pragma unroll
        for (int j2 = 0; j2 < 4; j2++){
            int e = e0 + j2;
            int c = e / 3;
            int d = e - c*3;
            float vv = (float)sVij[pl*128 + c];
            o[j2] = fmaf(vv, sC[pl*4+d], va[j2] + vj[j2]);
        }
        __builtin_nontemporal_store(o, (ffrag4*)(oBase + idx));
    }
}

extern "C" void kernel_launch(void* const* d_in, const int* in_sizes, int n_in,
                              void* d_out, int out_size, void* d_ws, size_t ws_size,
                              hipStream_t stream){
    const float* xi      = (const float*)d_in[0];
    const float* r_ij    = (const float*)d_in[1];
    const float* cos_ij  = (const float*)d_in[2];
    const float* f_ij    = (const float*)d_in[3];
    const float* nmask   = (const float*)d_in[4];
    const float* fW1     = (const float*)d_in[5];
    const float* fb1     = (const float*)d_in[6];
    const float* fW2     = (const float*)d_in[7];
    const float* fb2     = (const float*)d_in[8];
    const float* in2f_W  = (const float*)d_in[9];
    const float* f2W     = (const float*)d_in[10];
    const float* f2b     = (const float*)d_in[11];
    const float* aW1     = (const float*)d_in[12];
    const float* ab1     = (const float*)d_in[13];
    const float* aW2     = (const float*)d_in[14];
    const float* ab2     = (const float*)d_in[15];
    const float* pW1     = (const float*)d_in[16];
    const float* pb1     = (const float*)d_in[17];
    const float* pW2     = (const float*)d_in[18];
    const float* pb2     = (const float*)d_in[19];
    const float* eW1     = (const float*)d_in[20];
    const float* eb1     = (const float*)d_in[21];
    const float* eW2     = (const float*)d_in[22];
    const float* eb2     = (const float*)d_in[23];
    const int*  nbrs     = (const int*)d_in[24];

    float* out_vi = (float*)d_out;             // [B,A,NCB] fp32
    float* outV   = (float*)d_out + BA*NCB;    // [B,A,N,NCB,3] fp32

    k_wt<<<56, 256, 0, stream>>>(fW1, fW2, f2W, pW1, pW2, eW1, eW2);
    k_yi<<<BA, NF, 0, stream>>>(xi, in2f_W);

    k_main<<<BA, 256, 0, stream>>>(r_ij, cos_ij, f_ij, nmask, nbrs,
                                   fb1, fb2, f2b,
                                   aW1, ab1, aW2, ab2,
                                   pb1, pb2, eb1, eb2,
                                   out_vi);

    k_V<<<PAIRS/64, 256, 0, stream>>>(cos_ij, nbrs, outV);
}

// Round 10
// 249.072 us; speedup vs baseline: 1.0542x; 1.0542x over previous
//
#include <hip/hip_runtime.h>
#include <hip/hip_bf16.h>
#include <math.h>

#define B 4
#define A 256
#define NN 64
#define NCB 128
#define NF 128
#define NSB 50
#define BA (B*A)
#define PAIRS (BA*NN)

typedef __bf16 bf;
typedef __attribute__((ext_vector_type(8))) __bf16 bfrag8;
typedef __attribute__((ext_vector_type(4))) float ffrag4;

// ---- module-scope scratch (never touches inputs / d_ws) ----
__device__ __attribute__((aligned(16))) bf    g_yib[BA*NF];             // bf16(xi @ in2f_W)
__device__ __attribute__((aligned(16))) bf    g_vij[(size_t)PAIRS*NCB]; // bf16 vij stash (16 MB)
__device__ __attribute__((aligned(16))) float g_vik[BA*NCB*3];          // fp32 Vik rows [ba][c*3+d]
// transposed bf16 weights, layout [n][k] (k contiguous). tf1 padded to K=64.
__device__ __attribute__((aligned(16))) bf g_tf1[NF*64];
__device__ __attribute__((aligned(16))) bf g_tf2[NF*NF];
__device__ __attribute__((aligned(16))) bf g_tfo[NF*NF];
__device__ __attribute__((aligned(16))) bf g_tp1[NF*NF];
__device__ __attribute__((aligned(16))) bf g_tp2[NF*NF];
__device__ __attribute__((aligned(16))) bf g_te1[NF*NF];
__device__ __attribute__((aligned(16))) bf g_te2[NF*NF];

// fast ssp: softplus(x)-ln2 via hw v_exp_f32/v_log_f32
__device__ __forceinline__ float ssp(float x){
    float e = __expf(-fabsf(x));
    return fmaxf(x, 0.f) + __logf(1.f + e) - 0.6931471805599453f;
}

// ---- weight pre-transpose: W[k][n] fp32 -> Wt[n][k] bf16 (tf1 K-pad to 64) ----
__global__ __launch_bounds__(256)
void k_wt(const float* __restrict__ f1, const float* __restrict__ f2,
          const float* __restrict__ fo, const float* __restrict__ p1,
          const float* __restrict__ p2, const float* __restrict__ e1,
          const float* __restrict__ e2){
    int s = blockIdx.x >> 3, part = blockIdx.x & 7;
    const float* src; bf* dst; int kb, realK;
    if (s == 0){ src = f1; dst = g_tf1; kb = 6; realK = NSB; }
    else {
        kb = 7; realK = 128;
        src = (s==1)?f2:(s==2)?fo:(s==3)?p1:(s==4)?p2:(s==5)?e1:e2;
        dst = (s==1)?g_tf2:(s==2)?g_tfo:(s==3)?g_tp1:(s==4)?g_tp2:(s==5)?g_te1:g_te2;
    }
    int total = NF << kb;
    int chunk = total >> 3;
    int end = (part + 1) * chunk;
    for (int e = part*chunk + threadIdx.x; e < end; e += 256){
        int n = e >> kb, k = e & ((1<<kb)-1);
        dst[e] = (k < realK) ? (bf)src[k*NF + n] : (bf)0.f;
    }
}

// ---- g_yib[row][f] = bf16( xi[row,:] @ in2f_W[:,f] ) ----
__global__ __launch_bounds__(NF)
void k_yi(const float* __restrict__ xi, const float* __restrict__ W){
    int row = blockIdx.x, f = threadIdx.x;
    __shared__ float x[NCB];
    x[f] = xi[row*NCB + f];
    __syncthreads();
    float s = 0.f;
    #pragma unroll 16
    for (int c = 0; c < NCB; c++) s += x[c]*W[c*NF + f];
    g_yib[row*NF + f] = (bf)s;
}

// ---- QUARTER-tile staging (32 n-rows), coalesced; r5 layout otherwise ----
__device__ __forceinline__ void stage_w128q(bf* __restrict__ sW, const bf* __restrict__ g,
                                            int qtr, int tid){
    // 32 n-rows x 128 k, LDS stride 136; 512 x 16B chunks, 2/thread
    #pragma unroll
    for (int i = 0; i < 2; i++){
        int cid = i*256 + tid;
        int r = cid >> 4, ch = cid & 15;
        *(bfrag8*)&sW[r*136 + ch*8] = *(const bfrag8*)&g[(qtr*32 + r)*128 + ch*8];
    }
}
__device__ __forceinline__ void stage_w64q(bf* __restrict__ sW, const bf* __restrict__ g,
                                           int qtr, int tid){
    // 32 n-rows x 64 k, LDS stride 72; 256 x 16B chunks, 1/thread
    int r = tid >> 3, ch = tid & 7;
    *(bfrag8*)&sW[r*72 + ch*8] = *(const bfrag8*)&g[(qtr*32 + r)*64 + ch*8];
}
__device__ __forceinline__ void gemm4q(const bf* __restrict__ sW, const bfrag8 afr[4],
                                       ffrag4 acc[2], int q, int c16){
    #pragma unroll
    for (int nt = 0; nt < 2; nt++){
        ffrag4 a = {0.f,0.f,0.f,0.f};
        #pragma unroll
        for (int kt = 0; kt < 4; kt++){
            bfrag8 bv = *(const bfrag8*)&sW[(nt*16 + c16)*136 + kt*32 + q*8];
            a = __builtin_amdgcn_mfma_f32_16x16x32_bf16(afr[kt], bv, a, 0, 0, 0);
        }
        acc[nt] = a;
    }
}
__device__ __forceinline__ void gemm2q(const bf* __restrict__ sW, const bfrag8 afr[2],
                                       ffrag4 acc[2], int q, int c16){
    #pragma unroll
    for (int nt = 0; nt < 2; nt++){
        ffrag4 a = {0.f,0.f,0.f,0.f};
        #pragma unroll
        for (int kt = 0; kt < 2; kt++){
            bfrag8 bv = *(const bfrag8*)&sW[(nt*16 + c16)*72 + kt*32 + q*8];
            a = __builtin_amdgcn_mfma_f32_16x16x32_bf16(afr[kt], bv, a, 0, 0, 0);
        }
        acc[nt] = a;
    }
}

#define RDA4(DST) { _Pragma("unroll") for (int kt = 0; kt < 4; kt++) \
    DST[kt] = *(const bfrag8*)&sX[arow*136 + kt*32 + q*8]; }

// epilogue macros (Q = quarter 0..3), writes wave-private rows
#define EPI_SSP(BIASP, Q) \
    { _Pragma("unroll") for (int nt = 0; nt < 2; nt++){ \
        int col = ((Q)*2 + nt)*16 + c16; \
        float bias = BIASP[col]; \
        _Pragma("unroll") for (int rg = 0; rg < 4; rg++){ \
            int row = w*16 + q*4 + rg; \
            sX[row*136 + col] = (bf)ssp(acc[nt][rg] + bias); \
        } } }

#define EPI_LIN(BIASP, Q) \
    { _Pragma("unroll") for (int nt = 0; nt < 2; nt++){ \
        int col = ((Q)*2 + nt)*16 + c16; \
        float bias = BIASP[col]; \
        _Pragma("unroll") for (int rg = 0; rg < 4; rg++){ \
            int row = w*16 + q*4 + rg; \
            sX[row*136 + col] = (bf)(acc[nt][rg] + bias); \
        } } }

__global__ __launch_bounds__(256, 4)
void k_main(const float* __restrict__ r_ij, const float* __restrict__ cos_ij,
            const float* __restrict__ f_ij, const float* __restrict__ mask,
            const int* __restrict__ neighbors,
            const float* __restrict__ fb1, const float* __restrict__ fb2,
            const float* __restrict__ f2b,
            const float* __restrict__ aW1, const float* __restrict__ ab1,
            const float* __restrict__ aW2, const float* __restrict__ ab2,
            const float* __restrict__ pb1, const float* __restrict__ pb2,
            const float* __restrict__ eb1, const float* __restrict__ eb2,
            float* __restrict__ out_vi){
    const int tid  = threadIdx.x;
    const int ba   = blockIdx.x;          // atom (b*A + a)
    const int b    = ba >> 8;
    const int w    = tid >> 6;            // wave 0..3 -> rows w*16..w*16+15
    const int lane = tid & 63;
    const int q    = lane >> 4;
    const int c16  = lane & 15;
    const int arow = w*16 + c16;

    // Quarter-tile sW: LDS 27,648 B total -> 5 blocks/CU (r5 was 4).
    // Concurrency is the one lever that has moved k_main (r1->r5).
    __shared__ __attribute__((aligned(16))) bf sW[32*136];   // 8.7 KB staged weights
    __shared__ __attribute__((aligned(16))) bf sX[64*136];   // activations (wave-private rows)
    __shared__ float sCosM[64*4];
    __shared__ float sCr[64];
    __shared__ int   sJb[64];

    // ---- wave-private preload: f_ij rows -> sX (K zero-padded to 64) ----
    #pragma unroll
    for (int i = 0; i < 16; i++){
        int row = w*16 + i;
        float v = (lane < NSB) ? f_ij[((size_t)ba*64 + row)*NSB + lane] : 0.f;
        sX[row*136 + lane] = (bf)v;
    }
    if (lane < 16){
        int row = w*16 + lane;
        int p = ba*64 + row;
        sCosM[row*4+0] = cos_ij[p*3+0];
        sCosM[row*4+1] = cos_ij[p*3+1];
        sCosM[row*4+2] = cos_ij[p*3+2];
        sCosM[row*4+3] = mask[p];
        float r = r_ij[p];
        sCr[row] = (r < 5.f) ? 0.5f*(__cosf(r*0.62831853071795864769f) + 1.f) : 0.f;
        int j = neighbors[p] & (A-1);
        sJb[row] = (b*A + j)*NF;
    }
    // no barrier needed: sX/sCosM/sCr/sJb rows are wave-private (r3/r5-verified)

    bfrag8 afr[4], afrV[4], afr2[2]; ffrag4 acc[2];

    // ===== S1: h1 = ssp(f @ fW1 + fb1) -> sX  (K=64) =====
    #pragma unroll
    for (int kt = 0; kt < 2; kt++) afr2[kt] = *(const bfrag8*)&sX[arow*136 + kt*32 + q*8];
    #pragma unroll
    for (int qtr = 0; qtr < 4; qtr++){
        if (qtr) __syncthreads();
        stage_w64q(sW, g_tf1, qtr, tid);
        __syncthreads();
        gemm2q(sW, afr2, acc, q, c16);
        EPI_SSP(fb1, qtr);
    }
    RDA4(afr);                               // h1
    __syncthreads();

    // ===== S2: Wf = (h1 @ fW2 + fb2)*C ; u = yj*Wf -> sX =====
    #pragma unroll
    for (int qtr = 0; qtr < 4; qtr++){
        if (qtr) __syncthreads();
        stage_w128q(sW, g_tf2, qtr, tid);
        __syncthreads();
        gemm4q(sW, afr, acc, q, c16);
        #pragma unroll
        for (int nt = 0; nt < 2; nt++){
            int col = (qtr*2 + nt)*16 + c16;
            float bias = fb2[col];
            #pragma unroll
            for (int rg = 0; rg < 4; rg++){
                int row = w*16 + q*4 + rg;
                float wf = (acc[nt][rg] + bias) * sCr[row];
                sX[row*136 + col] = (bf)((float)g_yib[sJb[row] + col] * wf);
            }
        }
    }
    RDA4(afr);                               // u
    __syncthreads();

    // ===== S3: v = ssp(u @ f2W + f2b) -> sX ; vsum partials =====
    float vsAll[8];
    #pragma unroll
    for (int t = 0; t < 8; t++) vsAll[t] = 0.f;
    #pragma unroll
    for (int qtr = 0; qtr < 4; qtr++){
        if (qtr) __syncthreads();
        stage_w128q(sW, g_tfo, qtr, tid);
        __syncthreads();
        gemm4q(sW, afr, acc, q, c16);
        #pragma unroll
        for (int nt = 0; nt < 2; nt++){
            int col = (qtr*2 + nt)*16 + c16;
            float bias = f2b[col];
            #pragma unroll
            for (int rg = 0; rg < 4; rg++){
                int row = w*16 + q*4 + rg;
                float v = ssp(acc[nt][rg] + bias);
                sX[row*136 + col] = (bf)v;
                vsAll[qtr*2 + nt] += v * sCosM[row*4+3];
            }
        }
    }
    RDA4(afrV);                              // v — held in regs for S4 AND S6
    __syncthreads();

    // ===== S4: hp = ssp(v @ pW1 + pb1) -> sX =====
    #pragma unroll
    for (int qtr = 0; qtr < 4; qtr++){
        if (qtr) __syncthreads();
        stage_w128q(sW, g_tp1, qtr, tid);
        __syncthreads();
        gemm4q(sW, afrV, acc, q, c16);
        EPI_SSP(pb1, qtr);
    }
    RDA4(afr);                               // hp
    __syncthreads();

    // ===== S5: vij = hp @ pW2 + pb2 -> sX (linear) =====
    #pragma unroll
    for (int qtr = 0; qtr < 4; qtr++){
        if (qtr) __syncthreads();
        stage_w128q(sW, g_tp2, qtr, tid);
        __syncthreads();
        gemm4q(sW, afr, acc, q, c16);
        EPI_LIN(pb2, qtr);
    }
    // stream wave's vij rows -> g_vij (own-wave rows, complete after qtr 3)
    #pragma unroll
    for (int i = 0; i < 4; i++){
        int row = w*16 + i*4 + (lane >> 4);
        int cp  = c16*8;
        *(bfrag8*)&g_vij[((size_t)ba*64 + row)*128 + cp] = *(const bfrag8*)&sX[row*136 + cp];
    }
    __syncthreads();

    // ===== S6: he = ssp(v @ eW1 + eb1) -> sX  (input = afrV, still live) =====
    #pragma unroll
    for (int qtr = 0; qtr < 4; qtr++){
        if (qtr) __syncthreads();
        stage_w128q(sW, g_te1, qtr, tid);
        __syncthreads();
        gemm4q(sW, afrV, acc, q, c16);
        EPI_SSP(eb1, qtr);
    }
    RDA4(afr);                               // he
    __syncthreads();

    // ===== S7: vik = he @ eW2 + eb2 ; Vik partials (registers only) =====
    float vkAll[8][3];
    #pragma unroll
    for (int t = 0; t < 8; t++){ vkAll[t][0]=0.f; vkAll[t][1]=0.f; vkAll[t][2]=0.f; }
    #pragma unroll
    for (int qtr = 0; qtr < 4; qtr++){
        if (qtr) __syncthreads();
        stage_w128q(sW, g_te2, qtr, tid);
        __syncthreads();
        gemm4q(sW, afr, acc, q, c16);
        #pragma unroll
        for (int nt = 0; nt < 2; nt++){
            float bias = eb2[(qtr*2 + nt)*16 + c16];
            #pragma unroll
            for (int rg = 0; rg < 4; rg++){
                int row = w*16 + q*4 + rg;
                float vik = (acc[nt][rg] + bias) * sCosM[row*4+3];
                vkAll[qtr*2 + nt][0] += vik * sCosM[row*4+0];
                vkAll[qtr*2 + nt][1] += vik * sCosM[row*4+1];
                vkAll[qtr*2 + nt][2] += vik * sCosM[row*4+2];
            }
        }
    }

    // ===== finale: cross-wave reduction, reuse sX as scratch =====
    __syncthreads();
    float* const sVs   = (float*)sX;                   // 4*128 floats
    float* const sVk   = (float*)((char*)sX + 2048);   // 4*384 floats
    float* const sVsum = (float*)((char*)sX + 8192);   // 128 floats
    float* const sHa   = (float*)((char*)sX + 8704);   // 128 floats
    #pragma unroll
    for (int t = 0; t < 8; t++){
        float v = vsAll[t];
        v += __shfl_xor(v, 16);
        v += __shfl_xor(v, 32);
        if (q == 0) sVs[w*128 + t*16 + c16] = v;
    }
    #pragma unroll
    for (int t = 0; t < 8; t++){
        #pragma unroll
        for (int d = 0; d < 3; d++){
            float v = vkAll[t][d];
            v += __shfl_xor(v, 16);
            v += __shfl_xor(v, 32);
            if (q == 0) sVk[w*384 + (t*16 + c16)*3 + d] = v;
        }
    }
    __syncthreads();

    for (int e = tid; e < 384; e += 256)
        g_vik[ba*384 + e] = sVk[e] + sVk[384+e] + sVk[768+e] + sVk[1152+e];
    if (tid < 128)
        sVsum[tid] = sVs[tid] + sVs[128+tid] + sVs[256+tid] + sVs[384+tid];
    __syncthreads();
    if (tid < 128){
        float acc2 = ab1[tid];
        #pragma unroll 16
        for (int k = 0; k < 128; k++) acc2 += sVsum[k]*aW1[k*128 + tid];
        sHa[tid] = ssp(acc2);
    }
    __syncthreads();
    if (tid < 128){
        float acc2 = ab2[tid];
        #pragma unroll 16
        for (int k = 0; k < 128; k++) acc2 += sHa[k]*aW2[k*128 + tid];
        out_vi[ba*128 + tid] = acc2;
    }
}

// ---- V[p,c,d] = vij[p,c]*cos[p,d] + Vik[ba] + Vik[j]  (r5 version, unchanged) ----
__global__ __launch_bounds__(256)
void k_V(const float* __restrict__ cos_ij, const int* __restrict__ nbrs,
         float* __restrict__ outV){
    const int ba  = blockIdx.x;
    const int b   = ba >> 8;
    const int tid = threadIdx.x;
    __shared__ __attribute__((aligned(16))) bf sVij[64*128];   // 16 KB
    __shared__ float sVa[384];
    __shared__ float sC[64*4];
    __shared__ int   sJ[64];
    #pragma unroll
    for (int i = 0; i < 4; i++){
        int e8 = tid + i*256;
        *(bfrag8*)&sVij[e8*8] = *(const bfrag8*)&g_vij[(size_t)ba*8192 + e8*8];
    }
    for (int e = tid; e < 384; e += 256) sVa[e] = g_vik[ba*384 + e];
    if (tid < 64){
        int p = ba*64 + tid;
        sJ[tid] = (b*A + (nbrs[p] & (A-1)))*384;
        sC[tid*4+0] = cos_ij[p*3+0];
        sC[tid*4+1] = cos_ij[p*3+1];
        sC[tid*4+2] = cos_ij[p*3+2];
    }
    __syncthreads();
    float* const oBase = outV + (size_t)ba*24576;
    #pragma unroll 4
    for (int it = 0; it < 24; it++){
        int idx = (it*256 + tid)*4;            // 4 consecutive output floats
        int pl  = idx / 384;                   // pair-local
        int e0  = idx - pl*384;
        ffrag4 va = *(const ffrag4*)&sVa[e0];
        ffrag4 vj = *(const ffrag4*)(g_vik + sJ[pl] + e0);
        ffrag4 o;
        #pragma unroll
        for (int j2 = 0; j2 < 4; j2++){
            int e = e0 + j2;
            int c = e / 3;
            int d = e - c*3;
            float vv = (float)sVij[pl*128 + c];
            o[j2] = fmaf(vv, sC[pl*4+d], va[j2] + vj[j2]);
        }
        __builtin_nontemporal_store(o, (ffrag4*)(oBase + idx));
    }
}

extern "C" void kernel_launch(void* const* d_in, const int* in_sizes, int n_in,
                              void* d_out, int out_size, void* d_ws, size_t ws_size,
                              hipStream_t stream){
    const float* xi      = (const float*)d_in[0];
    const float* r_ij    = (const float*)d_in[1];
    const float* cos_ij  = (const float*)d_in[2];
    const float* f_ij    = (const float*)d_in[3];
    const float* nmask   = (const float*)d_in[4];
    const float* fW1     = (const float*)d_in[5];
    const float* fb1     = (const float*)d_in[6];
    const float* fW2     = (const float*)d_in[7];
    const float* fb2     = (const float*)d_in[8];
    const float* in2f_W  = (const float*)d_in[9];
    const float* f2W     = (const float*)d_in[10];
    const float* f2b     = (const float*)d_in[11];
    const float* aW1     = (const float*)d_in[12];
    const float* ab1     = (const float*)d_in[13];
    const float* aW2     = (const float*)d_in[14];
    const float* ab2     = (const float*)d_in[15];
    const float* pW1     = (const float*)d_in[16];
    const float* pb1     = (const float*)d_in[17];
    const float* pW2     = (const float*)d_in[18];
    const float* pb2     = (const float*)d_in[19];
    const float* eW1     = (const float*)d_in[20];
    const float* eb1     = (const float*)d_in[21];
    const float* eW2     = (const float*)d_in[22];
    const float* eb2     = (const float*)d_in[23];
    const int*  nbrs     = (const int*)d_in[24];

    float* out_vi = (float*)d_out;             // [B,A,NCB] fp32
    float* outV   = (float*)d_out + BA*NCB;    // [B,A,N,NCB,3] fp32

    k_wt<<<56, 256, 0, stream>>>(fW1, fW2, f2W, pW1, pW2, eW1, eW2);
    k_yi<<<BA, NF, 0, stream>>>(xi, in2f_W);

    k_main<<<BA, 256, 0, stream>>>(r_ij, cos_ij, f_ij, nmask, nbrs,
                                   fb1, fb2, f2b,
                                   aW1, ab1, aW2, ab2,
                                   pb1, pb2, eb1, eb2,
                                   out_vi);

    k_V<<<BA, 256, 0, stream>>>(cos_ij, nbrs, outV);
}

// Round 11
// 238.737 us; speedup vs baseline: 1.0998x; 1.0433x over previous
//
#include <hip/hip_runtime.h>
#include <hip/hip_bf16.h>
#include <math.h>

#define B 4
#define A 256
#define NN 64
#define NCB 128
#define NF 128
#define NSB 50
#define BA (B*A)
#define PAIRS (BA*NN)

typedef __bf16 bf;
typedef __attribute__((ext_vector_type(8))) __bf16 bfrag8;
typedef __attribute__((ext_vector_type(4))) float ffrag4;

// ---- module-scope scratch (never touches inputs / d_ws) ----
__device__ __attribute__((aligned(16))) bf    g_yib[BA*NF];             // bf16(xi @ in2f_W)
__device__ __attribute__((aligned(16))) bf    g_vij[(size_t)PAIRS*NCB]; // bf16 vij stash (16 MB)
__device__ __attribute__((aligned(16))) float g_vik[BA*NCB*3];          // fp32 Vik rows [ba][c*3+d]
// transposed bf16 weights, [n][k] k-contiguous, PRE-SWIZZLED: 16B chunk c of
// row n stored at position c^(n&15) (K=128) / c^(n&7) (K=64). This makes the
// LDS image (written LINEARLY by global_load_lds) conflict-free on frag reads.
__device__ __attribute__((aligned(16))) bf g_tf1[NF*64];
__device__ __attribute__((aligned(16))) bf g_tf2[NF*NF];
__device__ __attribute__((aligned(16))) bf g_tfo[NF*NF];
__device__ __attribute__((aligned(16))) bf g_tp1[NF*NF];
__device__ __attribute__((aligned(16))) bf g_tp2[NF*NF];
__device__ __attribute__((aligned(16))) bf g_te1[NF*NF];
__device__ __attribute__((aligned(16))) bf g_te2[NF*NF];

// fast ssp: softplus(x)-ln2 via hw v_exp_f32/v_log_f32
__device__ __forceinline__ float ssp(float x){
    float e = __expf(-fabsf(x));
    return fmaxf(x, 0.f) + __logf(1.f + e) - 0.6931471805599453f;
}

// direct global->LDS 16B copy (gfx950). LDS dest = uniform base + lane*16.
__device__ __forceinline__ void gload_lds16(const void* g, void* l){
    __builtin_amdgcn_global_load_lds(
        (const __attribute__((address_space(1))) void*)g,
        (__attribute__((address_space(3))) void*)l, 16, 0, 0);
}

// ---- weight pre-transpose: W[k][n] fp32 -> swizzled Wt bf16 ----
__global__ __launch_bounds__(256)
void k_wt(const float* __restrict__ f1, const float* __restrict__ f2,
          const float* __restrict__ fo, const float* __restrict__ p1,
          const float* __restrict__ p2, const float* __restrict__ e1,
          const float* __restrict__ e2){
    int s = blockIdx.x >> 3, part = blockIdx.x & 7;
    if (s == 0){
        // tf1: 128 rows x 64 k (K padded from 50), chunk swizzle c^(n&7)
        int base = part*1024;
        for (int e = base + threadIdx.x; e < base + 1024; e += 256){
            int n = e >> 6, kl = e & 63;
            int c = kl >> 3, j = kl & 7;
            int ok = ((c ^ (n & 7)) << 3) + j;          // original k
            g_tf1[e] = (ok < NSB) ? (bf)f1[ok*NF + n] : (bf)0.f;
        }
    } else {
        const float* src = (s==1)?f2:(s==2)?fo:(s==3)?p1:(s==4)?p2:(s==5)?e1:e2;
        bf* dst = (s==1)?g_tf2:(s==2)?g_tfo:(s==3)?g_tp1:(s==4)?g_tp2:(s==5)?g_te1:g_te2;
        int base = part*2048;
        for (int e = base + threadIdx.x; e < base + 2048; e += 256){
            int n = e >> 7, kl = e & 127;
            int c = kl >> 3, j = kl & 7;
            int ok = ((c ^ (n & 15)) << 3) + j;         // original k (<128 always)
            dst[e] = (bf)src[ok*NF + n];
        }
    }
}

// ---- g_yib[row][f] = bf16( xi[row,:] @ in2f_W[:,f] ) ----
__global__ __launch_bounds__(NF)
void k_yi(const float* __restrict__ xi, const float* __restrict__ W){
    int row = blockIdx.x, f = threadIdx.x;
    __shared__ float x[NCB];
    x[f] = xi[row*NCB + f];
    __syncthreads();
    float s = 0.f;
    #pragma unroll 16
    for (int c = 0; c < NCB; c++) s += x[c]*W[c*NF + f];
    g_yib[row*NF + f] = (bf)s;
}

// ---- staging via global_load_lds: linear LDS image of the swizzled rows ----
__device__ __forceinline__ void stage_w128(bf* __restrict__ sW, const bf* __restrict__ g,
                                           int half, int tid){
    // 64 rows x 128 k = 1024 x 16B chunks; wave wv covers chunks wv*256..+255
    int wv = tid >> 6, lane = tid & 63;
    const bf* gs = g + (size_t)half*8192;
    #pragma unroll
    for (int i = 0; i < 4; i++){
        int cb = wv*256 + i*64;
        gload_lds16(gs + (size_t)(cb + lane)*8, &sW[cb*8]);
    }
}
__device__ __forceinline__ void stage_w64(bf* __restrict__ sW, const bf* __restrict__ g,
                                          int half, int tid){
    // 64 rows x 64 k = 512 x 16B chunks; wave wv covers chunks wv*128..+127
    int wv = tid >> 6, lane = tid & 63;
    const bf* gs = g + (size_t)half*4096;
    #pragma unroll
    for (int i = 0; i < 2; i++){
        int cb = wv*128 + i*64;
        gload_lds16(gs + (size_t)(cb + lane)*8, &sW[cb*8]);
    }
}
// B-frag reads: row n stride 128 elems (256B); original chunk (kt*4+q) lives
// at position (kt*4+q)^(n&15). n&15==c16 -> 2 lanes/bank-quad (free 2-way).
__device__ __forceinline__ void gemm4(const bf* __restrict__ sW, const bfrag8 afr[4],
                                      ffrag4 acc[4], int q, int c16){
    #pragma unroll
    for (int nt = 0; nt < 4; nt++){
        int n = nt*16 + c16;
        ffrag4 a = {0.f,0.f,0.f,0.f};
        #pragma unroll
        for (int kt = 0; kt < 4; kt++){
            int ch = (kt*4 + q) ^ c16;
            bfrag8 bv = *(const bfrag8*)&sW[n*128 + ch*8];
            a = __builtin_amdgcn_mfma_f32_16x16x32_bf16(afr[kt], bv, a, 0, 0, 0);
        }
        acc[nt] = a;
    }
}
__device__ __forceinline__ void gemm2(const bf* __restrict__ sW, const bfrag8 afr[2],
                                      ffrag4 acc[4], int q, int c16){
    #pragma unroll
    for (int nt = 0; nt < 4; nt++){
        int n = nt*16 + c16;
        ffrag4 a = {0.f,0.f,0.f,0.f};
        #pragma unroll
        for (int kt = 0; kt < 2; kt++){
            int ch = (kt*4 + q) ^ (c16 & 7);
            bfrag8 bv = *(const bfrag8*)&sW[n*64 + ch*8];
            a = __builtin_amdgcn_mfma_f32_16x16x32_bf16(afr[kt], bv, a, 0, 0, 0);
        }
        acc[nt] = a;
    }
}

#define RDA4(DST) { _Pragma("unroll") for (int kt = 0; kt < 4; kt++) \
    DST[kt] = *(const bfrag8*)&sX[arow*136 + kt*32 + q*8]; }

// epilogue macros (H = half of current stage), all writes wave-private rows
#define EPI_SSP(BIASP, H) \
    { _Pragma("unroll") for (int nt = 0; nt < 4; nt++){ \
        int col = ((H)*4 + nt)*16 + c16; \
        float bias = BIASP[col]; \
        _Pragma("unroll") for (int rg = 0; rg < 4; rg++){ \
            int row = w*16 + q*4 + rg; \
            sX[row*136 + col] = (bf)ssp(acc[nt][rg] + bias); \
        } } }

#define EPI_LIN(BIASP, H) \
    { _Pragma("unroll") for (int nt = 0; nt < 4; nt++){ \
        int col = ((H)*4 + nt)*16 + c16; \
        float bias = BIASP[col]; \
        _Pragma("unroll") for (int rg = 0; rg < 4; rg++){ \
            int row = w*16 + q*4 + rg; \
            sX[row*136 + col] = (bf)(acc[nt][rg] + bias); \
        } } }

__global__ __launch_bounds__(256, 4)
void k_main(const float* __restrict__ r_ij, const float* __restrict__ cos_ij,
            const float* __restrict__ f_ij, const float* __restrict__ mask,
            const int* __restrict__ neighbors,
            const float* __restrict__ fb1, const float* __restrict__ fb2,
            const float* __restrict__ f2b,
            const float* __restrict__ aW1, const float* __restrict__ ab1,
            const float* __restrict__ aW2, const float* __restrict__ ab2,
            const float* __restrict__ pb1, const float* __restrict__ pb2,
            const float* __restrict__ eb1, const float* __restrict__ eb2,
            float* __restrict__ out_vi){
    const int tid  = threadIdx.x;
    const int ba   = blockIdx.x;          // atom (b*A + a)
    const int b    = ba >> 8;
    const int w    = tid >> 6;            // wave 0..3 -> rows w*16..w*16+15
    const int lane = tid & 63;
    const int q    = lane >> 4;
    const int c16  = lane & 15;
    const int arow = w*16 + c16;

    // LDS 35,328 B -> 4 blocks/CU (r5's proven concurrency level).
    __shared__ __attribute__((aligned(16))) bf sW[8192];     // 16 KB linear swizzled weights
    __shared__ __attribute__((aligned(16))) bf sX[64*136];   // activations (wave-private rows)
    __shared__ float sCosM[64*4];
    __shared__ float sCr[64];
    __shared__ int   sJb[64];

    // ---- wave-private preload: f_ij rows -> sX (K zero-padded to 64) ----
    #pragma unroll
    for (int i = 0; i < 16; i++){
        int row = w*16 + i;
        float v = (lane < NSB) ? f_ij[((size_t)ba*64 + row)*NSB + lane] : 0.f;
        sX[row*136 + lane] = (bf)v;
    }
    if (lane < 16){
        int row = w*16 + lane;
        int p = ba*64 + row;
        sCosM[row*4+0] = cos_ij[p*3+0];
        sCosM[row*4+1] = cos_ij[p*3+1];
        sCosM[row*4+2] = cos_ij[p*3+2];
        sCosM[row*4+3] = mask[p];
        float r = r_ij[p];
        sCr[row] = (r < 5.f) ? 0.5f*(__cosf(r*0.62831853071795864769f) + 1.f) : 0.f;
        int j = neighbors[p] & (A-1);
        sJb[row] = (b*A + j)*NF;
    }
    // no barrier needed: sX/sCosM/sCr/sJb rows are wave-private (r3/r5-verified)

    bfrag8 afr[4], afrV[4], afr2[2]; ffrag4 acc[4];

    // ===== S1: h1 = ssp(f @ fW1 + fb1) -> sX  (K=64) =====
    #pragma unroll
    for (int kt = 0; kt < 2; kt++) afr2[kt] = *(const bfrag8*)&sX[arow*136 + kt*32 + q*8];
    #pragma unroll
    for (int half = 0; half < 2; half++){
        if (half) __syncthreads();
        stage_w64(sW, g_tf1, half, tid);
        __syncthreads();
        gemm2(sW, afr2, acc, q, c16);
        EPI_SSP(fb1, half);
    }
    RDA4(afr);                               // h1
    __syncthreads();

    // ===== S2: Wf = (h1 @ fW2 + fb2)*C ; u = yj*Wf -> sX =====
    #pragma unroll
    for (int half = 0; half < 2; half++){
        if (half) __syncthreads();
        stage_w128(sW, g_tf2, half, tid);
        __syncthreads();
        gemm4(sW, afr, acc, q, c16);
        #pragma unroll
        for (int nt = 0; nt < 4; nt++){
            int col = (half*4 + nt)*16 + c16;
            float bias = fb2[col];
            #pragma unroll
            for (int rg = 0; rg < 4; rg++){
                int row = w*16 + q*4 + rg;
                float wf = (acc[nt][rg] + bias) * sCr[row];
                sX[row*136 + col] = (bf)((float)g_yib[sJb[row] + col] * wf);
            }
        }
    }
    RDA4(afr);                               // u
    __syncthreads();

    // ===== S3: v = ssp(u @ f2W + f2b) -> sX ; vsum partials =====
    float vsAll[8];
    #pragma unroll
    for (int t = 0; t < 8; t++) vsAll[t] = 0.f;
    #pragma unroll
    for (int half = 0; half < 2; half++){
        if (half) __syncthreads();
        stage_w128(sW, g_tfo, half, tid);
        __syncthreads();
        gemm4(sW, afr, acc, q, c16);
        #pragma unroll
        for (int nt = 0; nt < 4; nt++){
            int col = (half*4 + nt)*16 + c16;
            float bias = f2b[col];
            #pragma unroll
            for (int rg = 0; rg < 4; rg++){
                int row = w*16 + q*4 + rg;
                float v = ssp(acc[nt][rg] + bias);
                sX[row*136 + col] = (bf)v;
                vsAll[half*4 + nt] += v * sCosM[row*4+3];
            }
        }
    }
    RDA4(afrV);                              // v — held in regs for S4 AND S6
    __syncthreads();

    // ===== S4: hp = ssp(v @ pW1 + pb1) -> sX =====
    #pragma unroll
    for (int half = 0; half < 2; half++){
        if (half) __syncthreads();
        stage_w128(sW, g_tp1, half, tid);
        __syncthreads();
        gemm4(sW, afrV, acc, q, c16);
        EPI_SSP(pb1, half);
    }
    RDA4(afr);                               // hp
    __syncthreads();

    // ===== S5: vij = hp @ pW2 + pb2 -> sX (linear) =====
    #pragma unroll
    for (int half = 0; half < 2; half++){
        if (half) __syncthreads();
        stage_w128(sW, g_tp2, half, tid);
        __syncthreads();
        gemm4(sW, afr, acc, q, c16);
        EPI_LIN(pb2, half);
    }
    // stream wave's vij rows -> g_vij (own-wave rows)
    #pragma unroll
    for (int i = 0; i < 4; i++){
        int row = w*16 + i*4 + (lane >> 4);
        int cp  = c16*8;
        *(bfrag8*)&g_vij[((size_t)ba*64 + row)*128 + cp] = *(const bfrag8*)&sX[row*136 + cp];
    }
    __syncthreads();

    // ===== S6: he = ssp(v @ eW1 + eb1) -> sX  (input = afrV, still live) =====
    #pragma unroll
    for (int half = 0; half < 2; half++){
        if (half) __syncthreads();
        stage_w128(sW, g_te1, half, tid);
        __syncthreads();
        gemm4(sW, afrV, acc, q, c16);
        EPI_SSP(eb1, half);
    }
    RDA4(afr);                               // he
    __syncthreads();

    // ===== S7: vik = he @ eW2 + eb2 ; Vik partials (registers only) =====
    float vkAll[8][3];
    #pragma unroll
    for (int t = 0; t < 8; t++){ vkAll[t][0]=0.f; vkAll[t][1]=0.f; vkAll[t][2]=0.f; }
    #pragma unroll
    for (int half = 0; half < 2; half++){
        if (half) __syncthreads();
        stage_w128(sW, g_te2, half, tid);
        __syncthreads();
        gemm4(sW, afr, acc, q, c16);
        #pragma unroll
        for (int nt = 0; nt < 4; nt++){
            float bias = eb2[(half*4 + nt)*16 + c16];
            #pragma unroll
            for (int rg = 0; rg < 4; rg++){
                int row = w*16 + q*4 + rg;
                float vik = (acc[nt][rg] + bias) * sCosM[row*4+3];
                vkAll[half*4 + nt][0] += vik * sCosM[row*4+0];
                vkAll[half*4 + nt][1] += vik * sCosM[row*4+1];
                vkAll[half*4 + nt][2] += vik * sCosM[row*4+2];
            }
        }
    }

    // ===== finale: cross-wave reduction, reuse sX as scratch =====
    __syncthreads();
    float* const sVs   = (float*)sX;                   // 4*128 floats
    float* const sVk   = (float*)((char*)sX + 2048);   // 4*384 floats
    float* const sVsum = (float*)((char*)sX + 8192);   // 128 floats
    float* const sHa   = (float*)((char*)sX + 8704);   // 128 floats
    #pragma unroll
    for (int t = 0; t < 8; t++){
        float v = vsAll[t];
        v += __shfl_xor(v, 16);
        v += __shfl_xor(v, 32);
        if (q == 0) sVs[w*128 + t*16 + c16] = v;
    }
    #pragma unroll
    for (int t = 0; t < 8; t++){
        #pragma unroll
        for (int d = 0; d < 3; d++){
            float v = vkAll[t][d];
            v += __shfl_xor(v, 16);
            v += __shfl_xor(v, 32);
            if (q == 0) sVk[w*384 + (t*16 + c16)*3 + d] = v;
        }
    }
    __syncthreads();

    for (int e = tid; e < 384; e += 256)
        g_vik[ba*384 + e] = sVk[e] + sVk[384+e] + sVk[768+e] + sVk[1152+e];
    if (tid < 128)
        sVsum[tid] = sVs[tid] + sVs[128+tid] + sVs[256+tid] + sVs[384+tid];
    __syncthreads();
    if (tid < 128){
        float acc2 = ab1[tid];
        #pragma unroll 16
        for (int k = 0; k < 128; k++) acc2 += sVsum[k]*aW1[k*128 + tid];
        sHa[tid] = ssp(acc2);
    }
    __syncthreads();
    if (tid < 128){
        float acc2 = ab2[tid];
        #pragma unroll 16
        for (int k = 0; k < 128; k++) acc2 += sHa[k]*aW2[k*128 + tid];
        out_vi[ba*128 + tid] = acc2;
    }
}

// ---- V[p,c,d] = vij[p,c]*cos[p,d] + Vik[ba] + Vik[j]  (r5 version, unchanged) ----
__global__ __launch_bounds__(256)
void k_V(const float* __restrict__ cos_ij, const int* __restrict__ nbrs,
         float* __restrict__ outV){
    const int ba  = blockIdx.x;
    const int b   = ba >> 8;
    const int tid = threadIdx.x;
    __shared__ __attribute__((aligned(16))) bf sVij[64*128];   // 16 KB
    __shared__ float sVa[384];
    __shared__ float sC[64*4];
    __shared__ int   sJ[64];
    #pragma unroll
    for (int i = 0; i < 4; i++){
        int e8 = tid + i*256;
        *(bfrag8*)&sVij[e8*8] = *(const bfrag8*)&g_vij[(size_t)ba*8192 + e8*8];
    }
    for (int e = tid; e < 384; e += 256) sVa[e] = g_vik[ba*384 + e];
    if (tid < 64){
        int p = ba*64 + tid;
        sJ[tid] = (b*A + (nbrs[p] & (A-1)))*384;
        sC[tid*4+0] = cos_ij[p*3+0];
        sC[tid*4+1] = cos_ij[p*3+1];
        sC[tid*4+2] = cos_ij[p*3+2];
    }
    __syncthreads();
    float* const oBase = outV + (size_t)ba*24576;
    #pragma unroll 4
    for (int it = 0; it < 24; it++){
        int idx = (it*256 + tid)*4;            // 4 consecutive output floats
        int pl  = idx / 384;                   // pair-local
        int e0  = idx - pl*384;
        ffrag4 va = *(const ffrag4*)&sVa[e0];
        ffrag4 vj = *(const ffrag4*)(g_vik + sJ[pl] + e0);
        ffrag4 o;
        #pragma unroll
        for (int j2 = 0; j2 < 4; j2++){
            int e = e0 + j2;
            int c = e / 3;
            int d = e - c*3;
            float vv = (float)sVij[pl*128 + c];
            o[j2] = fmaf(vv, sC[pl*4+d], va[j2] + vj[j2]);
        }
        __builtin_nontemporal_store(o, (ffrag4*)(oBase + idx));
    }
}

extern "C" void kernel_launch(void* const* d_in, const int* in_sizes, int n_in,
                              void* d_out, int out_size, void* d_ws, size_t ws_size,
                              hipStream_t stream){
    const float* xi      = (const float*)d_in[0];
    const float* r_ij    = (const float*)d_in[1];
    const float* cos_ij  = (const float*)d_in[2];
    const float* f_ij    = (const float*)d_in[3];
    const float* nmask   = (const float*)d_in[4];
    const float* fW1     = (const float*)d_in[5];
    const float* fb1     = (const float*)d_in[6];
    const float* fW2     = (const float*)d_in[7];
    const float* fb2     = (const float*)d_in[8];
    const float* in2f_W  = (const float*)d_in[9];
    const float* f2W     = (const float*)d_in[10];
    const float* f2b     = (const float*)d_in[11];
    const float* aW1     = (const float*)d_in[12];
    const float* ab1     = (const float*)d_in[13];
    const float* aW2     = (const float*)d_in[14];
    const float* ab2     = (const float*)d_in[15];
    const float* pW1     = (const float*)d_in[16];
    const float* pb1     = (const float*)d_in[17];
    const float* pW2     = (const float*)d_in[18];
    const float* pb2     = (const float*)d_in[19];
    const float* eW1     = (const float*)d_in[20];
    const float* eb1     = (const float*)d_in[21];
    const float* eW2     = (const float*)d_in[22];
    const float* eb2     = (const float*)d_in[23];
    const int*  nbrs     = (const int*)d_in[24];

    float* out_vi = (float*)d_out;             // [B,A,NCB] fp32
    float* outV   = (float*)d_out + BA*NCB;    // [B,A,N,NCB,3] fp32

    k_wt<<<56, 256, 0, stream>>>(fW1, fW2, f2W, pW1, pW2, eW1, eW2);
    k_yi<<<BA, NF, 0, stream>>>(xi, in2f_W);

    k_main<<<BA, 256, 0, stream>>>(r_ij, cos_ij, f_ij, nmask, nbrs,
                                   fb1, fb2, f2b,
                                   aW1, ab1, aW2, ab2,
                                   pb1, pb2, eb1, eb2,
                                   out_vi);

    k_V<<<BA, 256, 0, stream>>>(cos_ij, nbrs, outV);
}